// Round 3
// baseline (114.898 us; speedup 1.0000x reference)
//
#include <hip/hip_runtime.h>
#include <math.h>

#define BB 64
#define TT 2048
#define DD 512
#define UU 10
#define S_CHUNKS 16
#define CHUNK_T (TT / S_CHUNKS)   // 128 t per block, 32 per wave, 8 batches of 4
#define NB (CHUNK_T / 16)         // 8 pipelined batches per wave

__device__ __forceinline__ float fast_tanh(float x) {
    // tanh(x) = 1 - 2/(1+e^{2x}); robust at +-inf
    return 1.0f - 2.0f / (1.0f + __expf(2.0f * x));
}

// Scores are bounded: |s| <= |b_s| + sum|W_s| (tanh in [-1,1]) ~ 4, so exp(s)
// never overflows and softmax needs NO max subtraction: p = exp(s), w = p/sum(p).
__global__ __launch_bounds__(256) void attn_pass1(
    const float* __restrict__ Eo, const float* __restrict__ H,
    const float* __restrict__ W_eo, const float* __restrict__ b_eo,
    const float* __restrict__ W_h, const float* __restrict__ b_h,
    const float* __restrict__ W_s, const float* __restrict__ b_s,
    float* __restrict__ pexp, float* __restrict__ pc)
{
    const int b     = blockIdx.y;
    const int chunk = blockIdx.x;
    const int tid   = threadIdx.x;
    const int wave  = tid >> 6;
    const int lane  = tid & 63;

    // ---- hb[u] = (H[b]*W_h)[u] + b_h[u] + b_eo[u]  (once per wave)
    float hacc[UU];
    #pragma unroll
    for (int u = 0; u < UU; ++u) hacc[u] = 0.f;
    const float* Hb = H + (size_t)b * DD;
    #pragma unroll
    for (int k = 0; k < DD / 64; ++k) {
        float hv = Hb[k * 64 + lane];
        const float* wr = W_h + (size_t)(k * 64 + lane) * UU;
        #pragma unroll
        for (int u = 0; u < UU; ++u) hacc[u] += hv * wr[u];
    }
    #pragma unroll
    for (int off = 1; off < 64; off <<= 1) {
        #pragma unroll
        for (int u = 0; u < UU; ++u) hacc[u] += __shfl_xor(hacc[u], off, 64);
    }
    float hb[UU];
    #pragma unroll
    for (int u = 0; u < UU; ++u) hb[u] = hacc[u] + b_h[u] + b_eo[u];

    float wsv[UU];
    #pragma unroll
    for (int u = 0; u < UU; ++u) wsv[u] = W_s[u];   // uniform -> scalar loads
    const float bs = b_s[0];

    // ---- per-lane W_eo slice (80 VGPRs, reused for all t)
    float wv[8][UU];
    #pragma unroll
    for (int k = 0; k < 2; ++k) {
        #pragma unroll
        for (int j = 0; j < 4; ++j) {
            const float* wr = W_eo + (size_t)(k * 256 + 4 * lane + j) * UU;
            #pragma unroll
            for (int u = 0; u < UU; ++u) wv[k * 4 + j][u] = wr[u];
        }
    }

    float l = 0.f;
    float c[8];
    #pragma unroll
    for (int j = 0; j < 8; ++j) c[j] = 0.f;

    const int  t0w  = chunk * CHUNK_T + wave * (CHUNK_T / 4);
    const bool lo32 = (lane & 32) == 0;
    const bool lo16 = (lane & 16) == 0;
    const float* rowbase = Eo + (size_t)b * TT * DD + 4 * lane;

    // Software-pipelined e-loads: double buffer, FULLY unrolled loop so all
    // buffer indices are compile-time (runtime-indexed arrays -> scratch).
    float4 eb[2][4][2];
    #pragma unroll
    for (int tt = 0; tt < 4; ++tt) {
        const float* row = rowbase + (size_t)(t0w + tt) * DD;
        eb[0][tt][0] = *(const float4*)(row);
        eb[0][tt][1] = *(const float4*)(row + 256);
    }

    #pragma unroll
    for (int i = 0; i < NB; ++i) {
        const int cur = i & 1, nxt = cur ^ 1;
        // prefetch batch i+1 while computing batch i
        if (i + 1 < NB) {
            #pragma unroll
            for (int tt = 0; tt < 4; ++tt) {
                const float* row = rowbase + (size_t)(t0w + (i + 1) * 4 + tt) * DD;
                eb[nxt][tt][0] = *(const float4*)(row);
                eb[nxt][tt][1] = *(const float4*)(row + 256);
            }
        }
        const int tb = t0w + i * 4;

        float e[4][8];
        #pragma unroll
        for (int tt = 0; tt < 4; ++tt) {
            e[tt][0] = eb[cur][tt][0].x; e[tt][1] = eb[cur][tt][0].y;
            e[tt][2] = eb[cur][tt][0].z; e[tt][3] = eb[cur][tt][0].w;
            e[tt][4] = eb[cur][tt][1].x; e[tt][5] = eb[cur][tt][1].y;
            e[tt][6] = eb[cur][tt][1].z; e[tt][7] = eb[cur][tt][1].w;
        }

        // per-lane partial projections for 4 t's
        float acc[4][UU];
        #pragma unroll
        for (int tt = 0; tt < 4; ++tt) {
            #pragma unroll
            for (int u = 0; u < UU; ++u) acc[tt][u] = 0.f;
            #pragma unroll
            for (int j = 0; j < 8; ++j) {
                #pragma unroll
                for (int u = 0; u < UU; ++u) acc[tt][u] += e[tt][j] * wv[j][u];
            }
        }

        // fold-reduce: 2 select-folds put t0..t3 into 16-lane groups, then a
        // 4-level butterfly reduces all four t's simultaneously.
        float r[UU];
        #pragma unroll
        for (int u = 0; u < UU; ++u) {
            float y0 = lo32 ? acc[0][u] : acc[2][u];
            float o0 = lo32 ? acc[2][u] : acc[0][u];
            y0 += __shfl_xor(o0, 32, 64);
            float y1 = lo32 ? acc[1][u] : acc[3][u];
            float o1 = lo32 ? acc[3][u] : acc[1][u];
            y1 += __shfl_xor(o1, 32, 64);
            float z  = lo16 ? y0 : y1;
            float oz = lo16 ? y1 : y0;
            z += __shfl_xor(oz, 16, 64);
            z += __shfl_xor(z, 8, 64);
            z += __shfl_xor(z, 4, 64);
            z += __shfl_xor(z, 2, 64);
            z += __shfl_xor(z, 1, 64);
            r[u] = z;   // group g = lane>>4 holds full proj of t = tb + g
        }

        // score -> p for this lane's group-t
        float s = bs;
        #pragma unroll
        for (int u = 0; u < UU; ++u) s += wsv[u] * fast_tanh(r[u] + hb[u]);
        float p = __expf(s);

        if ((lane & 15) == 0) pexp[(size_t)b * TT + tb + (lane >> 4)] = p;

        // broadcast the 4 p's; accumulate unnormalized context (no rescale)
        float p0 = __shfl(p, 0, 64);
        float p1 = __shfl(p, 16, 64);
        float p2 = __shfl(p, 32, 64);
        float p3 = __shfl(p, 48, 64);
        l += (p0 + p1) + (p2 + p3);
        #pragma unroll
        for (int j = 0; j < 8; ++j)
            c[j] += p0 * e[0][j] + p1 * e[1][j] + p2 * e[2][j] + p3 * e[3][j];
    }

    // ---- combine the block's 4 waves in LDS (l folded into pc via epilogue)
    __shared__ float sc[4][DD];
    #pragma unroll
    for (int k = 0; k < 2; ++k) {
        #pragma unroll
        for (int j = 0; j < 4; ++j)
            sc[wave][k * 256 + 4 * lane + j] = c[k * 4 + j];
    }
    __syncthreads();

    const int pidx = b * S_CHUNKS + chunk;
    for (int d = tid; d < DD; d += 256) {
        pc[(size_t)pidx * DD + d] = (sc[0][d] + sc[1][d]) + (sc[2][d] + sc[3][d]);
    }
}

// Fused epilogue: per batch b -- l = sum(pexp), context = sum(pc)/l,
// weight = pexp/l. One block per b.
__global__ __launch_bounds__(256) void attn_epilogue(
    const float* __restrict__ pexp, const float* __restrict__ pc,
    float* __restrict__ ctx_out, float* __restrict__ wout)
{
    const int b = blockIdx.x;
    const int tid = threadIdx.x;
    const int wave = tid >> 6;

    // l = sum over 2048 pexp values
    float s = 0.f;
    #pragma unroll
    for (int k = 0; k < TT / 256; ++k) s += pexp[(size_t)b * TT + k * 256 + tid];
    #pragma unroll
    for (int off = 1; off < 64; off <<= 1) s += __shfl_xor(s, off, 64);

    __shared__ float sl[4];
    if ((tid & 63) == 0) sl[wave] = s;
    __syncthreads();
    const float l = (sl[0] + sl[1]) + (sl[2] + sl[3]);
    const float inv = 1.0f / l;

    #pragma unroll
    for (int d = tid; d < DD; d += 256) {
        float v = 0.f;
        #pragma unroll
        for (int sss = 0; sss < S_CHUNKS; ++sss)
            v += pc[((size_t)(b * S_CHUNKS + sss)) * DD + d];
        ctx_out[(size_t)b * DD + d] = v * inv;
    }
    #pragma unroll
    for (int t = tid; t < TT; t += 256)
        wout[(size_t)b * TT + t] = pexp[(size_t)b * TT + t] * inv;
}

extern "C" void kernel_launch(void* const* d_in, const int* in_sizes, int n_in,
                              void* d_out, int out_size, void* d_ws, size_t ws_size,
                              hipStream_t stream) {
    const float* Eo   = (const float*)d_in[0];
    const float* H    = (const float*)d_in[1];
    const float* W_eo = (const float*)d_in[2];
    const float* b_eo = (const float*)d_in[3];
    const float* W_h  = (const float*)d_in[4];
    const float* b_h  = (const float*)d_in[5];
    const float* W_s  = (const float*)d_in[6];
    const float* b_s  = (const float*)d_in[7];

    // ws layout (floats): pexp[B*T] | pc[B*S*D]
    float* pexp = (float*)d_ws;
    float* pc   = pexp + (size_t)BB * TT;

    float* out_ctx = (float*)d_out;                 // [B, D]
    float* out_w   = out_ctx + (size_t)BB * DD;     // [B, T, 1]

    dim3 gridA(S_CHUNKS, BB);
    attn_pass1<<<gridA, 256, 0, stream>>>(Eo, H, W_eo, b_eo, W_h, b_h, W_s, b_s,
                                          pexp, pc);
    attn_epilogue<<<BB, 256, 0, stream>>>(pexp, pc, out_ctx, out_w);
}